// Round 18
// baseline (357.006 us; speedup 1.0000x reference)
//
#include <hip/hip_runtime.h>
#include <stdint.h>

#define DI __device__ __forceinline__

constexpr int Bn = 32, Cc = 64, Wn = 96, Hn = 96, Ln = 32, NG = 128, OUTC = 256;
constexpr int SEQ = 96;
constexpr long long NPIX = (long long)Bn * Wn * Hn;   // 294912
constexpr int GRAM_BLOCKS = 256;
constexpr int PIX_PER_BLOCK = (int)(NPIX / GRAM_BLOCKS); // 1152

typedef __attribute__((ext_vector_type(8))) short bf16x8;
typedef __attribute__((ext_vector_type(4))) float f32x4;

constexpr float LOG2E  = 1.44269504088896340736f;
constexpr float TWOL2E = 2.88539008177792681472f;

DI float exp2_(float x) { return __builtin_amdgcn_exp2f(x); }   // v_exp_f32
DI float rcp_(float x)  { return __builtin_amdgcn_rcpf(x); }    // v_rcp_f32 (~1ulp)
DI float bf2f(unsigned short u) { return __uint_as_float(((unsigned)u) << 16); }
DI unsigned short f2bf(float f) {
    unsigned u = __float_as_uint(f);
    u += 0x7FFFu + ((u >> 16) & 1u);   // RNE
    return (unsigned short)(u >> 16);
}

// ---------------------------------------------------------------------------
// x transpose: [B,C,W,H] f32 -> xT[chain=(b,w)][t=h][c] bf16.
// ---------------------------------------------------------------------------
__global__ __launch_bounds__(256)
void transpose_x(const float* __restrict__ x, unsigned short* __restrict__ xT)
{
    __shared__ alignas(16) unsigned char xs[96 * 128];
    const int tid = threadIdx.x;
    const int b = blockIdx.x / 96, q = blockIdx.x % 96;
    for (int i = tid; i < 1536; i += 256) {
        int c = i / 24, h4 = i - c * 24;
        float4 v = *(const float4*)(x + (((size_t)b * 64 + c) * 96 + q) * 96 + 4 * h4);
        float vv[4] = {v.x, v.y, v.z, v.w};
#pragma unroll
        for (int j = 0; j < 4; ++j) {
            int h = 4 * h4 + j;
            *(unsigned short*)(xs + h * 128 + ((c * 2) ^ ((h & 7) << 4))) = f2bf(vv[j]);
        }
    }
    __syncthreads();
    unsigned short* ob = xT + (size_t)blockIdx.x * 6144;
    for (int i = tid; i < 768; i += 256) {
        int row = i >> 3, k8 = i & 7;
        bf16x8 p = *(const bf16x8*)(xs + row * 128 + ((k8 * 16) ^ ((row & 7) << 4)));
        *(bf16x8*)(ob + (size_t)i * 8) = p;
    }
}

// ---------------------------------------------------------------------------
// FUSED BiLSTM (R18 = R17 split structure + 2 units per wave). R17 evidence:
// relaxed barrier changed nothing (-2.4us) -> the ~1200cyc/step non-issue
// time is schedulable stall (ds_read ~120cyc + MFMA + serial trans chains),
// exposed because the s-split removed ILP. R13's interleave failed at 73%
// issue occupancy; R17 waves are ~40% -> interleaving unit B into unit A's
// stalls should pay now. Block = 2 waves owns units A=gpair, B=gpair+96
// (same dir -> SHARED weight regs); wave wv computes s-group wv of BOTH.
// One barrier per 2 unit-steps. Grid 192 x 128.
// ---------------------------------------------------------------------------
#define FLOADU(UN, XA, XB, STI)                                                \
    if ((STI) < 96) {                                                          \
        const int tl_ = dir ? 95 - (STI) : (STI);                              \
        XA = *(const bf16x8*)(xTb##UN + (size_t)tl_ * 64);                     \
        XB = *(const bf16x8*)(xTb##UN + (size_t)tl_ * 64 + 32);                \
    }

#define PPROJ(UN, XA, XB)                                                      \
    _Pragma("unroll")                                                          \
    for (int g_ = 0; g_ < 4; ++g_) {                                           \
        f32x4 tp_ = __builtin_amdgcn_mfma_f32_16x16x32_bf16(ax0[g_], XA, bc[g_], 0, 0, 0); \
        xac##UN[g_] = __builtin_amdgcn_mfma_f32_16x16x32_bf16(ax1[g_], XB, tp_, 0, 0, 0);  \
    }

#define RSTEPU(UN)                                                             \
    {                                                                          \
        const bf16x8 hu = *(const bf16x8*)(hcur##UN + n_ * 80 + rg * 16);      \
        f32x4 ac_[4];                                                          \
        _Pragma("unroll")                                                      \
        for (int g_ = 0; g_ < 4; ++g_)                                         \
            ac_[g_] = __builtin_amdgcn_mfma_f32_16x16x32_bf16(ah[g_], hu, xac##UN[g_], 0, 0, 0); \
        unsigned short hs[4];                                                  \
        _Pragma("unroll")                                                      \
        for (int j = 0; j < 4; ++j) {                                          \
            const float iv = rcp_(1.f + exp2_(-ac_[0][j]));                    \
            const float fv = rcp_(1.f + exp2_(-ac_[1][j]));                    \
            const float gr = rcp_(1.f + exp2_(-ac_[2][j]));                    \
            const float gv = fmaf(2.f, gr, -1.f);                              \
            const float ov = rcp_(1.f + exp2_(-ac_[3][j]));                    \
            cc##UN[j] = fmaf(fv, cc##UN[j], iv * gv);                          \
            const float r_ = rcp_(exp2_(cc##UN[j] * TWOL2E) + 1.f);            \
            const float t2 = -2.f * ov;                                        \
            hs[j] = f2bf(fmaf(t2, r_, ov));                                    \
        }                                                                      \
        ushort4 hp; hp.x = hs[0]; hp.y = hs[1]; hp.z = hs[2]; hp.w = hs[3];    \
        *(ushort4*)(hnxt##UN + n_ * 80 + wv * 32 + rg * 8) = hp;               \
        *(ushort4*)optr##UN = hp;                                              \
        optr##UN += odelta;                                                    \
    }

#define STEP_SYNC                                                              \
    asm volatile("s_waitcnt lgkmcnt(0)" ::: "memory");                         \
    __builtin_amdgcn_s_barrier();                                              \
    __builtin_amdgcn_sched_barrier(0);                                         \
    { unsigned char* t_ = hcurA; hcurA = hnxtA; hnxtA = t_; }                  \
    { unsigned char* t_ = hcurB; hcurB = hnxtB; hnxtB = t_; }

template<int VERT>
__global__ __launch_bounds__(128, 1)
void lstm_fused(const unsigned short* __restrict__ xT,
                const float* __restrict__ wih_f, const float* __restrict__ whh_f,
                const float* __restrict__ bih_f, const float* __restrict__ bhh_f,
                const float* __restrict__ wih_b, const float* __restrict__ whh_b,
                const float* __restrict__ bih_b, const float* __restrict__ bhh_b,
                unsigned short* __restrict__ outU)
{
    __shared__ alignas(16) unsigned char hbufA[2][16 * 80];  // h[chain][32cells] bf16
    __shared__ alignas(16) unsigned char hbufB[2][16 * 80];

    const int tid = threadIdx.x;
    const int wv = tid >> 6, lane = tid & 63;
    const int dir = blockIdx.x & 1, gpair = blockIdx.x >> 1;   // gpair in [0,96)
    const int n_ = lane & 15, rg = lane >> 4;

    const int gA = gpair, gB = gpair + 96;
    const int chainA = gA * 16 + n_, chainB = gB * 16 + n_;
    const int bA = gA / 6, qA = (gA % 6) * 16 + n_;
    const int bB = gB / 6, qB = (gB % 6) * 16 + n_;

    const float* wih = dir ? wih_b : wih_f;
    const float* whh = dir ? whh_b : whh_f;
    const float* bih = dir ? bih_b : bih_f;
    const float* bhh = dir ? bhh_b : bhh_f;

    // Wave wv owns gate tiles tt = 2*g_ + wv (g_ = i,f,g,o), cells wv*16..+15.
    // Weights pre-scaled into exp2 domain (g-gate by 2*log2e); SHARED by both
    // units (same dir). Fragment mapping refcheck'd R9-R17.
    bf16x8 ah[4], ax0[4], ax1[4];
    f32x4 bc[4];
#pragma unroll
    for (int g_ = 0; g_ < 4; ++g_) {
        const int tt = 2 * g_ + wv;
        const float sc = (g_ == 2) ? TWOL2E : LOG2E;
        const float* sh = whh + (size_t)(tt * 16 + n_) * 32 + rg * 8;
        const float* sx = wih + (size_t)(tt * 16 + n_) * 64 + rg * 8;
        float4 h0 = *(const float4*)sh, h1 = *(const float4*)(sh + 4);
        float4 x0 = *(const float4*)sx, x1 = *(const float4*)(sx + 4);
        float4 x2 = *(const float4*)(sx + 32), x3 = *(const float4*)(sx + 36);
        ah[g_][0] = (short)f2bf(sc * h0.x); ah[g_][1] = (short)f2bf(sc * h0.y);
        ah[g_][2] = (short)f2bf(sc * h0.z); ah[g_][3] = (short)f2bf(sc * h0.w);
        ah[g_][4] = (short)f2bf(sc * h1.x); ah[g_][5] = (short)f2bf(sc * h1.y);
        ah[g_][6] = (short)f2bf(sc * h1.z); ah[g_][7] = (short)f2bf(sc * h1.w);
        ax0[g_][0] = (short)f2bf(sc * x0.x); ax0[g_][1] = (short)f2bf(sc * x0.y);
        ax0[g_][2] = (short)f2bf(sc * x0.z); ax0[g_][3] = (short)f2bf(sc * x0.w);
        ax0[g_][4] = (short)f2bf(sc * x1.x); ax0[g_][5] = (short)f2bf(sc * x1.y);
        ax0[g_][6] = (short)f2bf(sc * x1.z); ax0[g_][7] = (short)f2bf(sc * x1.w);
        ax1[g_][0] = (short)f2bf(sc * x2.x); ax1[g_][1] = (short)f2bf(sc * x2.y);
        ax1[g_][2] = (short)f2bf(sc * x2.z); ax1[g_][3] = (short)f2bf(sc * x2.w);
        ax1[g_][4] = (short)f2bf(sc * x3.x); ax1[g_][5] = (short)f2bf(sc * x3.y);
        ax1[g_][6] = (short)f2bf(sc * x3.z); ax1[g_][7] = (short)f2bf(sc * x3.w);
#pragma unroll
        for (int j = 0; j < 4; ++j) {
            const int g = tt * 16 + rg * 4 + j;
            bc[g_][j] = sc * (bih[g] + bhh[g]);
        }
    }

    const unsigned short* xTbA = xT + (size_t)chainA * 6144 + rg * 8;
    const unsigned short* xTbB = xT + (size_t)chainB * 6144 + rg * 8;

    const int t0 = dir ? 95 : 0;
    const size_t o0A = VERT ? ((((size_t)bA * 96 + t0) * 96 + qA) * 64)
                            : ((((size_t)bA * 96 + qA) * 96 + t0) * 64);
    const size_t o0B = VERT ? ((((size_t)bB * 96 + t0) * 96 + qB) * 64)
                            : ((((size_t)bB * 96 + qB) * 96 + t0) * 64);
    unsigned short* optrA = outU + o0A + dir * 32 + wv * 16 + rg * 4;
    unsigned short* optrB = outU + o0B + dir * 32 + wv * 16 + rg * 4;
    const ptrdiff_t odelta = (ptrdiff_t)(dir ? -1 : 1) * (VERT ? 6144 : 64);

    // zero initial h (buffer 0 of both units)
    for (int i = tid; i < 320; i += 128) {
        ((unsigned*)hbufA[0])[i] = 0u;
        ((unsigned*)hbufB[0])[i] = 0u;
    }

    unsigned char* hcurA = hbufA[0]; unsigned char* hnxtA = hbufA[1];
    unsigned char* hcurB = hbufB[0]; unsigned char* hnxtB = hbufB[1];

    float ccA[4] = {0.f, 0.f, 0.f, 0.f};
    float ccB[4] = {0.f, 0.f, 0.f, 0.f};
    f32x4 xacA[4], xacB[4];
    bf16x8 xaA0, xbA0, xaA1, xbA1, xaA2, xbA2;
    bf16x8 xaB0, xbB0, xaB1, xbB1, xaB2, xbB2;

    FLOADU(A, xaA0, xbA0, 0) FLOADU(B, xaB0, xbB0, 0)
    FLOADU(A, xaA1, xbA1, 1) FLOADU(B, xaB1, xbB1, 1)
    PPROJ(A, xaA0, xbA0)
    PPROJ(B, xaB0, xbB0)
    __syncthreads();

    for (int st = 0; st < 96; st += 3) {
        FLOADU(A, xaA2, xbA2, st + 2)
        FLOADU(B, xaB2, xbB2, st + 2)
        RSTEPU(A)
        PPROJ(A, xaA1, xbA1)
        RSTEPU(B)
        PPROJ(B, xaB1, xbB1)
        STEP_SYNC

        FLOADU(A, xaA0, xbA0, st + 3)
        FLOADU(B, xaB0, xbB0, st + 3)
        RSTEPU(A)
        PPROJ(A, xaA2, xbA2)
        RSTEPU(B)
        PPROJ(B, xaB2, xbB2)
        STEP_SYNC

        FLOADU(A, xaA1, xbA1, st + 4)
        FLOADU(B, xaB1, xbB1, st + 4)
        RSTEPU(A)
        PPROJ(A, xaA0, xbA0)
        RSTEPU(B)
        PPROJ(B, xaB0, xbB0)
        STEP_SYNC
    }
}

// ---------------------------------------------------------------------------
// Partial Gram (64x64) + channel-sum via MFMA (R14/R15, passed). Symmetry =>
// A and B fragments read the SAME transposed LDS image XsT[c][p] (144B rows).
// ---------------------------------------------------------------------------
__global__ __launch_bounds__(256, 2)
void gram_partial(const unsigned short* __restrict__ hh, float* __restrict__ part)
{
    __shared__ alignas(16) unsigned char xsT[2][64 * 144];  // bf16 [c][p], 144B rows
    __shared__ float sumb[16][64];

    const int tid = threadIdx.x;
    const int wv = tid >> 6, lane = tid & 63;
    const int lrow = lane & 15, lkg = lane >> 4;
    const int cq = tid & 15, pr = tid >> 4;

    float csum[4] = {0.f, 0.f, 0.f, 0.f};
    f32x4 acc[4];
#pragma unroll
    for (int n = 0; n < 4; ++n) acc[n] = (f32x4){0.f, 0.f, 0.f, 0.f};

    const size_t pix0 = (size_t)blockIdx.x * PIX_PER_BLOCK;

    for (int tile = 0; tile < PIX_PER_BLOCK / 64; ++tile) {
        unsigned char* Xb = xsT[tile & 1];
#pragma unroll
        for (int r = 0; r < 4; ++r) {
            const int p = pr + r * 16;
            ushort4 v = *(const ushort4*)(hh + (pix0 + (size_t)tile * 64 + p) * 64 + cq * 4);
            csum[0] += bf2f(v.x); csum[1] += bf2f(v.y);
            csum[2] += bf2f(v.z); csum[3] += bf2f(v.w);
            *(unsigned short*)(Xb + (cq * 4 + 0) * 144 + p * 2) = v.x;
            *(unsigned short*)(Xb + (cq * 4 + 1) * 144 + p * 2) = v.y;
            *(unsigned short*)(Xb + (cq * 4 + 2) * 144 + p * 2) = v.z;
            *(unsigned short*)(Xb + (cq * 4 + 3) * 144 + p * 2) = v.w;
        }
        __syncthreads();
#pragma unroll
        for (int kc = 0; kc < 2; ++kc) {
            const int kb = (kc * 32 + lkg * 8) * 2;
            bf16x8 af = *(const bf16x8*)(Xb + (wv * 16 + lrow) * 144 + kb);
#pragma unroll
            for (int n = 0; n < 4; ++n) {
                bf16x8 bf_ = *(const bf16x8*)(Xb + (n * 16 + lrow) * 144 + kb);
                acc[n] = __builtin_amdgcn_mfma_f32_16x16x32_bf16(af, bf_, acc[n], 0, 0, 0);
            }
        }
    }

    *(float4*)&sumb[pr][cq * 4] = (float4){csum[0], csum[1], csum[2], csum[3]};
    __syncthreads();
    float* pb = part + (size_t)blockIdx.x * 4160;
    if (tid < 64) {
        float s = 0.f;
#pragma unroll
        for (int r = 0; r < 16; ++r) s += sumb[r][tid];
        pb[4096 + tid] = s;
    }
#pragma unroll
    for (int n = 0; n < 4; ++n)
#pragma unroll
        for (int r = 0; r < 4; ++r)
            pb[(wv * 16 + lkg * 4 + r) * 64 + n * 16 + lrow] = acc[n][r];
}

__global__ void gram_reduce(const float* __restrict__ part, float* __restrict__ M)
{
    int e = blockIdx.x * 256 + threadIdx.x;
    if (e >= 4160) return;
    double s = 0.0;
    for (int p = 0; p < GRAM_BLOCKS; ++p) s += (double)part[(size_t)p * 4160 + e];
    M[e] = (float)s;
}

// Per-output-channel affine coefficients A,B such that out = A*(w_o . u) + B.
__global__ __launch_bounds__(256)
void stats_kernel(const float* __restrict__ M, const float* __restrict__ cw,
                  const float* __restrict__ cb, const float* __restrict__ bg,
                  const float* __restrict__ bb,
                  float* __restrict__ Aout, float* __restrict__ Bout)
{
    __shared__ float Ml[4160];
    const int tid = threadIdx.x;
    for (int e = tid; e < 4160; e += 256) Ml[e] = M[e];
    __syncthreads();
    float wr[64];
#pragma unroll
    for (int c = 0; c < 64; ++c) wr[c] = bf2f(f2bf(cw[tid * 64 + c]));
    float s1 = 0.f;
#pragma unroll
    for (int c = 0; c < 64; ++c) s1 = fmaf(wr[c], Ml[4096 + c], s1);
    float s2 = 0.f;
    for (int c = 0; c < 64; ++c) {
        const float* Mr = &Ml[c * 64];
        float t = 0.f;
#pragma unroll
        for (int d = 0; d < 64; ++d) t = fmaf(wr[d], Mr[d], t);
        s2 = fmaf(wr[c], t, s2);
    }
    const double invN = 1.0 / (double)NPIX;
    double cbo = (double)cb[tid];
    double mu = (double)s1 * invN + cbo;
    double ey2 = (double)s2 * invN + 2.0 * cbo * ((double)s1 * invN) + cbo * cbo;
    double var = ey2 - mu * mu;
    double A = (double)bg[tid] / sqrt(var + 1e-5);
    Aout[tid] = (float)A;
    Bout[tid] = (float)((double)bb[tid] + A * (cbo - mu));
}

// ---------------------------------------------------------------------------
// Fused 1x1 conv + BN apply via MFMA. Block = (b,w): D[96 h][256 o].
// Nontemporal f32x4 stores (302MB streaming output, never re-read).
// ---------------------------------------------------------------------------
__global__ __launch_bounds__(512, 2)
void conv_bn_kernel(const unsigned short* __restrict__ hh, const float* __restrict__ cw,
                    const float* __restrict__ Aarr, const float* __restrict__ Barr,
                    float* __restrict__ out)
{
    __shared__ alignas(16) unsigned char UsB[96 * 128];    // bf16 U, swizzled
    __shared__ alignas(16) unsigned char WtB[256 * 128];   // bf16 conv W, swizzled

    const int tid = threadIdx.x;
    const int b = blockIdx.x / 96, w = blockIdx.x % 96;

    for (int i4 = tid; i4 < 4096; i4 += 512) {
        int wrow = i4 >> 4, k4 = i4 & 15;
        float4 v = *(const float4*)(cw + (size_t)wrow * 64 + k4 * 4);
        ushort4 p; p.x = f2bf(v.x); p.y = f2bf(v.y); p.z = f2bf(v.z); p.w = f2bf(v.w);
        *(ushort4*)(WtB + wrow * 128 + ((k4 * 8) ^ ((wrow & 7) << 4))) = p;
    }
    for (int i = tid; i < 1536; i += 512) {
        int row = i >> 4, k4 = i & 15;   // row = h
        ushort4 p = *(const ushort4*)(hh + (((size_t)b * 96 + row) * 96 + w) * 64 + k4 * 4);
        *(ushort4*)(UsB + row * 128 + ((k4 * 8) ^ ((row & 7) << 4))) = p;
    }
    __syncthreads();

    const int wv = tid >> 6, lane = tid & 63;
    const int mbase = (wv >> 2) * 48, nbase = (wv & 3) * 64;
    const int lrow = lane & 15, lk = (lane >> 4) * 8;

    f32x4 acc[3][4];
#pragma unroll
    for (int m = 0; m < 3; ++m)
#pragma unroll
        for (int n = 0; n < 4; ++n)
            acc[m][n] = (f32x4){0.f, 0.f, 0.f, 0.f};

#pragma unroll
    for (int ks = 0; ks < 2; ++ks) {
        const int kb = (ks * 32 + lk) * 2;
        bf16x8 am[3], bn[4];
#pragma unroll
        for (int m = 0; m < 3; ++m) {
            int row = mbase + m * 16 + lrow;
            am[m] = *(const bf16x8*)(UsB + row * 128 + (kb ^ ((row & 7) << 4)));
        }
#pragma unroll
        for (int n = 0; n < 4; ++n) {
            int o = nbase + n * 16 + lrow;
            bn[n] = *(const bf16x8*)(WtB + o * 128 + (kb ^ ((o & 7) << 4)));
        }
#pragma unroll
        for (int m = 0; m < 3; ++m)
#pragma unroll
            for (int n = 0; n < 4; ++n)
                acc[m][n] = __builtin_amdgcn_mfma_f32_16x16x32_bf16(am[m], bn[n], acc[m][n], 0, 0, 0);
    }

    const int hbase0 = (lane >> 4) * 4;
#pragma unroll
    for (int n = 0; n < 4; ++n) {
        const int o = nbase + n * 16 + lrow;
        const float Ao = Aarr[o], Bo = Barr[o];
        float* obase = out + (((size_t)b * 256 + o) * 96 + w) * 96;
#pragma unroll
        for (int m = 0; m < 3; ++m) {
            const int h0 = mbase + m * 16 + hbase0;
            f32x4 res;
            res[0] = fmaf(Ao, acc[m][n][0], Bo);
            res[1] = fmaf(Ao, acc[m][n][1], Bo);
            res[2] = fmaf(Ao, acc[m][n][2], Bo);
            res[3] = fmaf(Ao, acc[m][n][3], Bo);
            __builtin_nontemporal_store(res, (f32x4*)(obase + h0));
        }
    }
}

extern "C" void kernel_launch(void* const* d_in, const int* in_sizes, int n_in,
                              void* d_out, int out_size, void* d_ws, size_t ws_size,
                              hipStream_t stream)
{
    const float* x       = (const float*)d_in[0];
    const float* v_wih_f = (const float*)d_in[1];
    const float* v_whh_f = (const float*)d_in[2];
    const float* v_bih_f = (const float*)d_in[3];
    const float* v_bhh_f = (const float*)d_in[4];
    const float* v_wih_b = (const float*)d_in[5];
    const float* v_whh_b = (const float*)d_in[6];
    const float* v_bih_b = (const float*)d_in[7];
    const float* v_bhh_b = (const float*)d_in[8];
    const float* h_wih_f = (const float*)d_in[9];
    const float* h_whh_f = (const float*)d_in[10];
    const float* h_bih_f = (const float*)d_in[11];
    const float* h_bhh_f = (const float*)d_in[12];
    const float* h_wih_b = (const float*)d_in[13];
    const float* h_whh_b = (const float*)d_in[14];
    const float* h_bih_b = (const float*)d_in[15];
    const float* h_bhh_b = (const float*)d_in[16];
    const float* conv_w  = (const float*)d_in[17];
    const float* conv_b  = (const float*)d_in[18];
    const float* bn_g    = (const float*)d_in[19];
    const float* bn_b    = (const float*)d_in[20];
    float* out = (float*)d_out;

    // d_out (302 MB) doubles as scratch before conv_bn rewrites all of it:
    //   front 37.7 MB: xT (bf16 [chain=(b,w)][t=h][c]) — dead after pass 1
    //   @64 MB: gram partials (256 x 4160 f32 = 4.3 MB)
    //   tail 37.7 MB: v (bf16 [chain=(b,h)][t=w][c])  — vertical LSTM output
    const size_t v_elems = (size_t)Bn * Hn * Wn * 64;   // 18,874,368 bf16
    unsigned short* v_buf = (unsigned short*)(out + (size_t)out_size) - v_elems;
    unsigned short* xT = (unsigned short*)d_out;
    float* part = (float*)((char*)d_out + (64u << 20));

    // workspace layout
    unsigned short* hh = (unsigned short*)d_ws;                       // bf16 [B,H,W,64]
    char* wsb = (char*)d_ws;
    float* M    = (float*)(wsb + 37748736);                           // 4160 f32
    float* Aarr = M + 4160;
    float* Barr = Aarr + 256;

    // vertical pass: transpose x, then fused projection+recurrence
    transpose_x<<<3072, 256, 0, stream>>>(x, xT);
    lstm_fused<1><<<192, 128, 0, stream>>>(xT, v_wih_f, v_whh_f, v_bih_f, v_bhh_f,
                                           v_wih_b, v_whh_b, v_bih_b, v_bhh_b, v_buf);
    // horizontal pass: v is already [chain][t][c]
    lstm_fused<0><<<192, 128, 0, stream>>>(v_buf, h_wih_f, h_whh_f, h_bih_f, h_bhh_f,
                                           h_wih_b, h_whh_b, h_bih_b, h_bhh_b, hh);
    // conv + BN (affine-folded via Gram-matrix stats)
    gram_partial<<<GRAM_BLOCKS, 256, 0, stream>>>(hh, part);
    gram_reduce<<<17, 256, 0, stream>>>(part, M);
    stats_kernel<<<1, 256, 0, stream>>>(M, conv_w, conv_b, bn_g, bn_b, Aarr, Barr);
    conv_bn_kernel<<<3072, 512, 0, stream>>>(hh, conv_w, Aarr, Barr, out);
}

// Round 19
// 337.341 us; speedup vs baseline: 1.0583x; 1.0583x over previous
//
#include <hip/hip_runtime.h>
#include <stdint.h>

#define DI __device__ __forceinline__

constexpr int Bn = 32, Cc = 64, Wn = 96, Hn = 96, Ln = 32, NG = 128, OUTC = 256;
constexpr int SEQ = 96;
constexpr long long NPIX = (long long)Bn * Wn * Hn;   // 294912
constexpr int GRAM_BLOCKS = 256;
constexpr int PIX_PER_BLOCK = (int)(NPIX / GRAM_BLOCKS); // 1152

typedef __attribute__((ext_vector_type(8))) short bf16x8;
typedef __attribute__((ext_vector_type(4))) float f32x4;

constexpr float LOG2E  = 1.44269504088896340736f;
constexpr float TWOL2E = 2.88539008177792681472f;

DI float exp2_(float x) { return __builtin_amdgcn_exp2f(x); }   // v_exp_f32
DI float rcp_(float x)  { return __builtin_amdgcn_rcpf(x); }    // v_rcp_f32 (~1ulp)
DI float bf2f(unsigned short u) { return __uint_as_float(((unsigned)u) << 16); }
DI unsigned short f2bf(float f) {
    unsigned u = __float_as_uint(f);
    u += 0x7FFFu + ((u >> 16) & 1u);   // RNE
    return (unsigned short)(u >> 16);
}

// ---------------------------------------------------------------------------
// x transpose: [B,C,W,H] f32 -> xT[chain=(b,w)][t=h][c] bf16.
// ---------------------------------------------------------------------------
__global__ __launch_bounds__(256)
void transpose_x(const float* __restrict__ x, unsigned short* __restrict__ xT)
{
    __shared__ alignas(16) unsigned char xs[96 * 128];
    const int tid = threadIdx.x;
    const int b = blockIdx.x / 96, q = blockIdx.x % 96;
    for (int i = tid; i < 1536; i += 256) {
        int c = i / 24, h4 = i - c * 24;
        float4 v = *(const float4*)(x + (((size_t)b * 64 + c) * 96 + q) * 96 + 4 * h4);
        float vv[4] = {v.x, v.y, v.z, v.w};
#pragma unroll
        for (int j = 0; j < 4; ++j) {
            int h = 4 * h4 + j;
            *(unsigned short*)(xs + h * 128 + ((c * 2) ^ ((h & 7) << 4))) = f2bf(vv[j]);
        }
    }
    __syncthreads();
    unsigned short* ob = xT + (size_t)blockIdx.x * 6144;
    for (int i = tid; i < 768; i += 256) {
        int row = i >> 3, k8 = i & 7;
        bf16x8 p = *(const bf16x8*)(xs + row * 128 + ((k8 * 16) ^ ((row & 7) << 4)));
        *(bf16x8*)(ob + (size_t)i * 8) = p;
    }
}

// ---------------------------------------------------------------------------
// FUSED BiLSTM (R19 = R17 restored; best = 336.8us). R18 post-mortem: the
// 2-unit/block repack halved wave count 768->384 (37.5% SIMD coverage) and
// regressed to 357 — more waves beats per-wave ILP for this latency-bound
// step. Structure: 2 waves per unit, split by s-group. Wave wv owns gate
// tiles {wv,2+wv,4+wv,6+wv} = cells wv*16..+15 (self-contained cell update:
// 12 MFMA, 40 trans/lane/step). Cross-wave h via double-buffered LDS
// h[chain][32cells] (80B stride); relaxed per-step barrier = ds_write,
// s_waitcnt lgkmcnt(0), raw s_barrier, sched_barrier(0) — global stores and
// xT prefetch stay in flight (never drain vmcnt in the loop).
// Grid 384 x 128 = 768 waves (75% SIMD coverage).
// ---------------------------------------------------------------------------
#define FLOAD(XA, XB, STI)                                                     \
    if ((STI) < 96) {                                                          \
        const int tl_ = dir ? 95 - (STI) : (STI);                              \
        XA = *(const bf16x8*)(xTb + (size_t)tl_ * 64);                         \
        XB = *(const bf16x8*)(xTb + (size_t)tl_ * 64 + 32);                    \
    }

#define PPROJ(XA, XB)                                                          \
    _Pragma("unroll")                                                          \
    for (int g_ = 0; g_ < 4; ++g_) {                                           \
        f32x4 tp_ = __builtin_amdgcn_mfma_f32_16x16x32_bf16(ax0[g_], XA, bc[g_], 0, 0, 0); \
        xac[g_] = __builtin_amdgcn_mfma_f32_16x16x32_bf16(ax1[g_], XB, tp_, 0, 0, 0);      \
    }

#define RSTEP(STI)                                                             \
    {                                                                          \
        const bf16x8 hu = *(const bf16x8*)(hcur + n_ * 80 + rg * 16);          \
        f32x4 ac_[4];                                                          \
        _Pragma("unroll")                                                      \
        for (int g_ = 0; g_ < 4; ++g_)                                         \
            ac_[g_] = __builtin_amdgcn_mfma_f32_16x16x32_bf16(ah[g_], hu, xac[g_], 0, 0, 0); \
        unsigned short hs[4];                                                  \
        _Pragma("unroll")                                                      \
        for (int j = 0; j < 4; ++j) {                                          \
            const float iv = rcp_(1.f + exp2_(-ac_[0][j]));                    \
            const float fv = rcp_(1.f + exp2_(-ac_[1][j]));                    \
            const float gr = rcp_(1.f + exp2_(-ac_[2][j]));                    \
            const float gv = fmaf(2.f, gr, -1.f);                              \
            const float ov = rcp_(1.f + exp2_(-ac_[3][j]));                    \
            cc[j] = fmaf(fv, cc[j], iv * gv);                                  \
            const float r_ = rcp_(exp2_(cc[j] * TWOL2E) + 1.f);                \
            const float t2 = -2.f * ov;                                        \
            hs[j] = f2bf(fmaf(t2, r_, ov));                                    \
        }                                                                      \
        ushort4 hp; hp.x = hs[0]; hp.y = hs[1]; hp.z = hs[2]; hp.w = hs[3];    \
        *(ushort4*)(hnxt + n_ * 80 + wv * 32 + rg * 8) = hp;                   \
        *(ushort4*)optr = hp;                                                  \
        optr += odelta;                                                        \
        asm volatile("s_waitcnt lgkmcnt(0)" ::: "memory");                     \
        __builtin_amdgcn_s_barrier();                                          \
        __builtin_amdgcn_sched_barrier(0);                                     \
        { unsigned char* t_ = hcur; hcur = hnxt; hnxt = t_; }                  \
    }

template<int VERT>
__global__ __launch_bounds__(128, 1)
void lstm_fused(const unsigned short* __restrict__ xT,
                const float* __restrict__ wih_f, const float* __restrict__ whh_f,
                const float* __restrict__ bih_f, const float* __restrict__ bhh_f,
                const float* __restrict__ wih_b, const float* __restrict__ whh_b,
                const float* __restrict__ bih_b, const float* __restrict__ bhh_b,
                unsigned short* __restrict__ outU)
{
    __shared__ alignas(16) unsigned char hbuf[2][16 * 80];  // h[chain][32cells] bf16, 80B stride

    const int tid = threadIdx.x;
    const int wv = tid >> 6, lane = tid & 63;
    const int dir = blockIdx.x & 1, group = blockIdx.x >> 1;   // group in [0,192)
    const int n_ = lane & 15, rg = lane >> 4;
    const int chain = group * 16 + n_;
    const int b = group / 6;
    const int q = (group % 6) * 16 + n_;

    const float* wih = dir ? wih_b : wih_f;
    const float* whh = dir ? whh_b : whh_f;
    const float* bih = dir ? bih_b : bih_f;
    const float* bhh = dir ? bhh_b : bhh_f;

    // Wave wv owns gate tiles tt = 2*g_ + wv (g_ = i,f,g,o), cells wv*16..+15.
    // Weights pre-scaled into exp2 domain (g-gate by 2*log2e). Fragment
    // mapping refcheck'd R9-R17: lane (n_, rg): row = tt*16+n_, k = rg*8..+8.
    bf16x8 ah[4], ax0[4], ax1[4];
    f32x4 bc[4];
#pragma unroll
    for (int g_ = 0; g_ < 4; ++g_) {
        const int tt = 2 * g_ + wv;
        const float sc = (g_ == 2) ? TWOL2E : LOG2E;
        const float* sh = whh + (size_t)(tt * 16 + n_) * 32 + rg * 8;
        const float* sx = wih + (size_t)(tt * 16 + n_) * 64 + rg * 8;
        float4 h0 = *(const float4*)sh, h1 = *(const float4*)(sh + 4);
        float4 x0 = *(const float4*)sx, x1 = *(const float4*)(sx + 4);
        float4 x2 = *(const float4*)(sx + 32), x3 = *(const float4*)(sx + 36);
        ah[g_][0] = (short)f2bf(sc * h0.x); ah[g_][1] = (short)f2bf(sc * h0.y);
        ah[g_][2] = (short)f2bf(sc * h0.z); ah[g_][3] = (short)f2bf(sc * h0.w);
        ah[g_][4] = (short)f2bf(sc * h1.x); ah[g_][5] = (short)f2bf(sc * h1.y);
        ah[g_][6] = (short)f2bf(sc * h1.z); ah[g_][7] = (short)f2bf(sc * h1.w);
        ax0[g_][0] = (short)f2bf(sc * x0.x); ax0[g_][1] = (short)f2bf(sc * x0.y);
        ax0[g_][2] = (short)f2bf(sc * x0.z); ax0[g_][3] = (short)f2bf(sc * x0.w);
        ax0[g_][4] = (short)f2bf(sc * x1.x); ax0[g_][5] = (short)f2bf(sc * x1.y);
        ax0[g_][6] = (short)f2bf(sc * x1.z); ax0[g_][7] = (short)f2bf(sc * x1.w);
        ax1[g_][0] = (short)f2bf(sc * x2.x); ax1[g_][1] = (short)f2bf(sc * x2.y);
        ax1[g_][2] = (short)f2bf(sc * x2.z); ax1[g_][3] = (short)f2bf(sc * x2.w);
        ax1[g_][4] = (short)f2bf(sc * x3.x); ax1[g_][5] = (short)f2bf(sc * x3.y);
        ax1[g_][6] = (short)f2bf(sc * x3.z); ax1[g_][7] = (short)f2bf(sc * x3.w);
#pragma unroll
        for (int j = 0; j < 4; ++j) {
            const int g = tt * 16 + rg * 4 + j;
            bc[g_][j] = sc * (bih[g] + bhh[g]);
        }
    }

    const unsigned short* xTb = xT + (size_t)chain * 6144 + rg * 8;

    // running output pointer; this wave stores its s-group's pack only
    const int t0 = dir ? 95 : 0;
    const size_t o0 = VERT ? ((((size_t)b * 96 + t0) * 96 + q) * 64)
                           : ((((size_t)b * 96 + q) * 96 + t0) * 64);
    unsigned short* optr = outU + o0 + dir * 32 + wv * 16 + rg * 4;
    const ptrdiff_t odelta = (ptrdiff_t)(dir ? -1 : 1) * (VERT ? 6144 : 64);

    // zero initial h (buffer 0 only); both waves participate
    for (int i = tid; i < 320; i += 128) ((unsigned*)hbuf[0])[i] = 0u;

    unsigned char* hcur = hbuf[0];
    unsigned char* hnxt = hbuf[1];

    float cc[4] = {0.f, 0.f, 0.f, 0.f};
    f32x4 xac[4];
    bf16x8 xa0, xb0, xa1, xb1, xa2, xb2;
    FLOAD(xa0, xb0, 0)
    FLOAD(xa1, xb1, 1)
    PPROJ(xa0, xb0)
    __syncthreads();

    for (int st = 0; st < 96; st += 3) {
        FLOAD(xa2, xb2, st + 2)
        RSTEP(st)
        PPROJ(xa1, xb1)
        FLOAD(xa0, xb0, st + 3)
        RSTEP(st + 1)
        PPROJ(xa2, xb2)
        FLOAD(xa1, xb1, st + 4)
        RSTEP(st + 2)
        PPROJ(xa0, xb0)
    }
}

// ---------------------------------------------------------------------------
// Partial Gram (64x64) + channel-sum via MFMA (R14/R15, passed). Symmetry =>
// A and B fragments read the SAME transposed LDS image XsT[c][p] (144B rows).
// ---------------------------------------------------------------------------
__global__ __launch_bounds__(256, 2)
void gram_partial(const unsigned short* __restrict__ hh, float* __restrict__ part)
{
    __shared__ alignas(16) unsigned char xsT[2][64 * 144];  // bf16 [c][p], 144B rows
    __shared__ float sumb[16][64];

    const int tid = threadIdx.x;
    const int wv = tid >> 6, lane = tid & 63;
    const int lrow = lane & 15, lkg = lane >> 4;
    const int cq = tid & 15, pr = tid >> 4;

    float csum[4] = {0.f, 0.f, 0.f, 0.f};
    f32x4 acc[4];
#pragma unroll
    for (int n = 0; n < 4; ++n) acc[n] = (f32x4){0.f, 0.f, 0.f, 0.f};

    const size_t pix0 = (size_t)blockIdx.x * PIX_PER_BLOCK;

    for (int tile = 0; tile < PIX_PER_BLOCK / 64; ++tile) {
        unsigned char* Xb = xsT[tile & 1];
#pragma unroll
        for (int r = 0; r < 4; ++r) {
            const int p = pr + r * 16;
            ushort4 v = *(const ushort4*)(hh + (pix0 + (size_t)tile * 64 + p) * 64 + cq * 4);
            csum[0] += bf2f(v.x); csum[1] += bf2f(v.y);
            csum[2] += bf2f(v.z); csum[3] += bf2f(v.w);
            *(unsigned short*)(Xb + (cq * 4 + 0) * 144 + p * 2) = v.x;
            *(unsigned short*)(Xb + (cq * 4 + 1) * 144 + p * 2) = v.y;
            *(unsigned short*)(Xb + (cq * 4 + 2) * 144 + p * 2) = v.z;
            *(unsigned short*)(Xb + (cq * 4 + 3) * 144 + p * 2) = v.w;
        }
        __syncthreads();
#pragma unroll
        for (int kc = 0; kc < 2; ++kc) {
            const int kb = (kc * 32 + lkg * 8) * 2;
            bf16x8 af = *(const bf16x8*)(Xb + (wv * 16 + lrow) * 144 + kb);
#pragma unroll
            for (int n = 0; n < 4; ++n) {
                bf16x8 bf_ = *(const bf16x8*)(Xb + (n * 16 + lrow) * 144 + kb);
                acc[n] = __builtin_amdgcn_mfma_f32_16x16x32_bf16(af, bf_, acc[n], 0, 0, 0);
            }
        }
    }

    *(float4*)&sumb[pr][cq * 4] = (float4){csum[0], csum[1], csum[2], csum[3]};
    __syncthreads();
    float* pb = part + (size_t)blockIdx.x * 4160;
    if (tid < 64) {
        float s = 0.f;
#pragma unroll
        for (int r = 0; r < 16; ++r) s += sumb[r][tid];
        pb[4096 + tid] = s;
    }
#pragma unroll
    for (int n = 0; n < 4; ++n)
#pragma unroll
        for (int r = 0; r < 4; ++r)
            pb[(wv * 16 + lkg * 4 + r) * 64 + n * 16 + lrow] = acc[n][r];
}

__global__ void gram_reduce(const float* __restrict__ part, float* __restrict__ M)
{
    int e = blockIdx.x * 256 + threadIdx.x;
    if (e >= 4160) return;
    double s = 0.0;
    for (int p = 0; p < GRAM_BLOCKS; ++p) s += (double)part[(size_t)p * 4160 + e];
    M[e] = (float)s;
}

// Per-output-channel affine coefficients A,B such that out = A*(w_o . u) + B.
__global__ __launch_bounds__(256)
void stats_kernel(const float* __restrict__ M, const float* __restrict__ cw,
                  const float* __restrict__ cb, const float* __restrict__ bg,
                  const float* __restrict__ bb,
                  float* __restrict__ Aout, float* __restrict__ Bout)
{
    __shared__ float Ml[4160];
    const int tid = threadIdx.x;
    for (int e = tid; e < 4160; e += 256) Ml[e] = M[e];
    __syncthreads();
    float wr[64];
#pragma unroll
    for (int c = 0; c < 64; ++c) wr[c] = bf2f(f2bf(cw[tid * 64 + c]));
    float s1 = 0.f;
#pragma unroll
    for (int c = 0; c < 64; ++c) s1 = fmaf(wr[c], Ml[4096 + c], s1);
    float s2 = 0.f;
    for (int c = 0; c < 64; ++c) {
        const float* Mr = &Ml[c * 64];
        float t = 0.f;
#pragma unroll
        for (int d = 0; d < 64; ++d) t = fmaf(wr[d], Mr[d], t);
        s2 = fmaf(wr[c], t, s2);
    }
    const double invN = 1.0 / (double)NPIX;
    double cbo = (double)cb[tid];
    double mu = (double)s1 * invN + cbo;
    double ey2 = (double)s2 * invN + 2.0 * cbo * ((double)s1 * invN) + cbo * cbo;
    double var = ey2 - mu * mu;
    double A = (double)bg[tid] / sqrt(var + 1e-5);
    Aout[tid] = (float)A;
    Bout[tid] = (float)((double)bb[tid] + A * (cbo - mu));
}

// ---------------------------------------------------------------------------
// Fused 1x1 conv + BN apply via MFMA. Block = (b,w): D[96 h][256 o].
// Nontemporal f32x4 stores (302MB streaming output, never re-read).
// ---------------------------------------------------------------------------
__global__ __launch_bounds__(512, 2)
void conv_bn_kernel(const unsigned short* __restrict__ hh, const float* __restrict__ cw,
                    const float* __restrict__ Aarr, const float* __restrict__ Barr,
                    float* __restrict__ out)
{
    __shared__ alignas(16) unsigned char UsB[96 * 128];    // bf16 U, swizzled
    __shared__ alignas(16) unsigned char WtB[256 * 128];   // bf16 conv W, swizzled

    const int tid = threadIdx.x;
    const int b = blockIdx.x / 96, w = blockIdx.x % 96;

    for (int i4 = tid; i4 < 4096; i4 += 512) {
        int wrow = i4 >> 4, k4 = i4 & 15;
        float4 v = *(const float4*)(cw + (size_t)wrow * 64 + k4 * 4);
        ushort4 p; p.x = f2bf(v.x); p.y = f2bf(v.y); p.z = f2bf(v.z); p.w = f2bf(v.w);
        *(ushort4*)(WtB + wrow * 128 + ((k4 * 8) ^ ((wrow & 7) << 4))) = p;
    }
    for (int i = tid; i < 1536; i += 512) {
        int row = i >> 4, k4 = i & 15;   // row = h
        ushort4 p = *(const ushort4*)(hh + (((size_t)b * 96 + row) * 96 + w) * 64 + k4 * 4);
        *(ushort4*)(UsB + row * 128 + ((k4 * 8) ^ ((row & 7) << 4))) = p;
    }
    __syncthreads();

    const int wv = tid >> 6, lane = tid & 63;
    const int mbase = (wv >> 2) * 48, nbase = (wv & 3) * 64;
    const int lrow = lane & 15, lk = (lane >> 4) * 8;

    f32x4 acc[3][4];
#pragma unroll
    for (int m = 0; m < 3; ++m)
#pragma unroll
        for (int n = 0; n < 4; ++n)
            acc[m][n] = (f32x4){0.f, 0.f, 0.f, 0.f};

#pragma unroll
    for (int ks = 0; ks < 2; ++ks) {
        const int kb = (ks * 32 + lk) * 2;
        bf16x8 am[3], bn[4];
#pragma unroll
        for (int m = 0; m < 3; ++m) {
            int row = mbase + m * 16 + lrow;
            am[m] = *(const bf16x8*)(UsB + row * 128 + (kb ^ ((row & 7) << 4)));
        }
#pragma unroll
        for (int n = 0; n < 4; ++n) {
            int o = nbase + n * 16 + lrow;
            bn[n] = *(const bf16x8*)(WtB + o * 128 + (kb ^ ((o & 7) << 4)));
        }
#pragma unroll
        for (int m = 0; m < 3; ++m)
#pragma unroll
            for (int n = 0; n < 4; ++n)
                acc[m][n] = __builtin_amdgcn_mfma_f32_16x16x32_bf16(am[m], bn[n], acc[m][n], 0, 0, 0);
    }

    const int hbase0 = (lane >> 4) * 4;
#pragma unroll
    for (int n = 0; n < 4; ++n) {
        const int o = nbase + n * 16 + lrow;
        const float Ao = Aarr[o], Bo = Barr[o];
        float* obase = out + (((size_t)b * 256 + o) * 96 + w) * 96;
#pragma unroll
        for (int m = 0; m < 3; ++m) {
            const int h0 = mbase + m * 16 + hbase0;
            f32x4 res;
            res[0] = fmaf(Ao, acc[m][n][0], Bo);
            res[1] = fmaf(Ao, acc[m][n][1], Bo);
            res[2] = fmaf(Ao, acc[m][n][2], Bo);
            res[3] = fmaf(Ao, acc[m][n][3], Bo);
            __builtin_nontemporal_store(res, (f32x4*)(obase + h0));
        }
    }
}

extern "C" void kernel_launch(void* const* d_in, const int* in_sizes, int n_in,
                              void* d_out, int out_size, void* d_ws, size_t ws_size,
                              hipStream_t stream)
{
    const float* x       = (const float*)d_in[0];
    const float* v_wih_f = (const float*)d_in[1];
    const float* v_whh_f = (const float*)d_in[2];
    const float* v_bih_f = (const float*)d_in[3];
    const float* v_bhh_f = (const float*)d_in[4];
    const float* v_wih_b = (const float*)d_in[5];
    const float* v_whh_b = (const float*)d_in[6];
    const float* v_bih_b = (const float*)d_in[7];
    const float* v_bhh_b = (const float*)d_in[8];
    const float* h_wih_f = (const float*)d_in[9];
    const float* h_whh_f = (const float*)d_in[10];
    const float* h_bih_f = (const float*)d_in[11];
    const float* h_bhh_f = (const float*)d_in[12];
    const float* h_wih_b = (const float*)d_in[13];
    const float* h_whh_b = (const float*)d_in[14];
    const float* h_bih_b = (const float*)d_in[15];
    const float* h_bhh_b = (const float*)d_in[16];
    const float* conv_w  = (const float*)d_in[17];
    const float* conv_b  = (const float*)d_in[18];
    const float* bn_g    = (const float*)d_in[19];
    const float* bn_b    = (const float*)d_in[20];
    float* out = (float*)d_out;

    // d_out (302 MB) doubles as scratch before conv_bn rewrites all of it:
    //   front 37.7 MB: xT (bf16 [chain=(b,w)][t=h][c]) — dead after pass 1
    //   @64 MB: gram partials (256 x 4160 f32 = 4.3 MB)
    //   tail 37.7 MB: v (bf16 [chain=(b,h)][t=w][c])  — vertical LSTM output
    const size_t v_elems = (size_t)Bn * Hn * Wn * 64;   // 18,874,368 bf16
    unsigned short* v_buf = (unsigned short*)(out + (size_t)out_size) - v_elems;
    unsigned short* xT = (unsigned short*)d_out;
    float* part = (float*)((char*)d_out + (64u << 20));

    // workspace layout
    unsigned short* hh = (unsigned short*)d_ws;                       // bf16 [B,H,W,64]
    char* wsb = (char*)d_ws;
    float* M    = (float*)(wsb + 37748736);                           // 4160 f32
    float* Aarr = M + 4160;
    float* Barr = Aarr + 256;

    // vertical pass: transpose x, then fused projection+recurrence
    transpose_x<<<3072, 256, 0, stream>>>(x, xT);
    lstm_fused<1><<<384, 128, 0, stream>>>(xT, v_wih_f, v_whh_f, v_bih_f, v_bhh_f,
                                           v_wih_b, v_whh_b, v_bih_b, v_bhh_b, v_buf);
    // horizontal pass: v is already [chain][t][c]
    lstm_fused<0><<<384, 128, 0, stream>>>(v_buf, h_wih_f, h_whh_f, h_bih_f, h_bhh_f,
                                           h_wih_b, h_whh_b, h_bih_b, h_bhh_b, hh);
    // conv + BN (affine-folded via Gram-matrix stats)
    gram_partial<<<GRAM_BLOCKS, 256, 0, stream>>>(hh, part);
    gram_reduce<<<17, 256, 0, stream>>>(part, M);
    stats_kernel<<<1, 256, 0, stream>>>(M, conv_w, conv_b, bn_g, bn_b, Aarr, Barr);
    conv_bn_kernel<<<3072, 512, 0, stream>>>(hh, conv_w, Aarr, Barr, out);
}